// Round 2
// baseline (1555.315 us; speedup 1.0000x reference)
//
#include <hip/hip_runtime.h>
#include <hip/hip_bf16.h>

// FeaStConv x4 on MI355X.
//  (1) (xj-xi)@u = p[src]-p[dst] with p = x@u per node.
//  (2) out_i = sum_h (sum_j q_h x_j) @ W_h  -> gather x_j into per-head
//      aggregates Agg[N, H*Cin], then ONE dense GEMM per layer.
// All intermediates fp32. Input dtypes (fp32 vs bf16 floats, int32 vs int64
// edge_index) are DETECTED at runtime (flags in ws) — the reference generates
// fp32 + int64, but the harness may narrow either.

#define HH 6
constexpr int NN = 50000;
constexpr int NE = 1600000;

static __device__ __forceinline__ float b2f(__hip_bfloat16 v) { return __bfloat162float(v); }

// dual-dtype float load: f32 ? fp32[i] : bf16[i]
static __device__ __forceinline__ float ldf(const void* p, int i, int f32) {
    return f32 ? ((const float*)p)[i] : b2f(((const __hip_bfloat16*)p)[i]);
}
// dual-dtype edge-index load (element index i in the logical [2*NE] array)
static __device__ __forceinline__ int ldi(const int* e32, int i, int i64) {
    return i64 ? e32[2 * i] : e32[i];  // little-endian low word; values < 2^31
}

// ---------------- dtype detection ----------------
// flags[0] = 1 if float inputs are fp32 ; flags[1] = 1 if edge_index is int64
__global__ void k_detect(const void* pos, const void* ei, int* flags) {
    __shared__ float smax[256];
    __shared__ int anynz;
    int t = threadIdx.x;
    if (t == 0) anynz = 0;
    const __hip_bfloat16* pb = (const __hip_bfloat16*)pos;
    float m = 0.f;
    for (int i = t; i < 2048; i += 256) {       // first 4KB — safe either dtype
        float v = fabsf(b2f(pb[i]));
        if (v != v) v = 1e30f;                  // NaN pattern => fp32 garbage
        m = fmaxf(m, v);
    }
    smax[t] = m;
    __syncthreads();
    for (int s = 128; s > 0; s >>= 1) {
        if (t < s) smax[t] = fmaxf(smax[t], smax[t + s]);
        __syncthreads();
    }
    const int* e32 = (const int*)ei;
    if (t < 128 && e32[2 * t + 1] != 0) anynz = 1;  // first 1KB — safe either way
    __syncthreads();
    if (t == 0) {
        flags[0] = (smax[0] > 1e6f) ? 1 : 0;    // bf16 N(0,1) stays < ~5
        flags[1] = anynz ? 0 : 1;               // all odd words zero => int64
    }
}

// ---------------- input assembly ----------------
__global__ void k_build_x0(const void* __restrict__ pos, const void* __restrict__ nrm,
                           float* __restrict__ x, const int* __restrict__ flags) {
    int f32 = flags[0];
    int i = blockIdx.x * blockDim.x + threadIdx.x;
    if (i >= NN) return;
#pragma unroll
    for (int j = 0; j < 3; j++) {
        x[i * 6 + j]     = ldf(pos, i * 3 + j, f32);
        x[i * 6 + 3 + j] = ldf(nrm, i * 3 + j, f32);
    }
}

// ---------------- CSR build (by dst) ----------------
__global__ void k_count(const int* __restrict__ ei, int* __restrict__ counts,
                        const int* __restrict__ flags) {
    int i64 = flags[1];
    int e = blockIdx.x * blockDim.x + threadIdx.x;
    if (e >= NE) return;
    atomicAdd(&counts[ldi(ei, NE + e, i64)], 1);
}

// single-block exclusive scan over NN counts
__global__ void __launch_bounds__(1024) k_scan(const int* __restrict__ counts,
                                               int* __restrict__ offsets) {
    __shared__ int wsum[16];
    __shared__ int s_running;
    int t = threadIdx.x;
    int lane = t & 63, wid = t >> 6;
    if (t == 0) s_running = 0;
    __syncthreads();
    for (int base = 0; base < NN; base += 1024) {
        int v = (base + t < NN) ? counts[base + t] : 0;
        int incl = v;
#pragma unroll
        for (int off = 1; off < 64; off <<= 1) {
            int n = __shfl_up(incl, off, 64);
            if (lane >= off) incl += n;
        }
        if (lane == 63) wsum[wid] = incl;
        __syncthreads();
        int wprefix = 0, total = 0;
#pragma unroll
        for (int wi = 0; wi < 16; wi++) {
            int s = wsum[wi];
            if (wi < wid) wprefix += s;
            total += s;
        }
        if (base + t < NN) offsets[base + t] = s_running + wprefix + (incl - v);
        __syncthreads();
        if (t == 0) s_running += total;
        __syncthreads();
    }
    if (t == 0) offsets[NN] = s_running;
}

__global__ void k_scatter(const int* __restrict__ ei, const int* __restrict__ offsets,
                          int* __restrict__ cursor, int* __restrict__ ssrc,
                          int* __restrict__ sdst, const int* __restrict__ flags) {
    int i64 = flags[1];
    int e = blockIdx.x * blockDim.x + threadIdx.x;
    if (e >= NE) return;
    int s = ldi(ei, e, i64), d = ldi(ei, NE + e, i64);
    int slot = offsets[d] + atomicAdd(&cursor[d], 1);
    ssrc[slot] = s;
    sdst[slot] = d;
}

// ---------------- p = x @ u  (wave per node) ----------------
template <int CIN>
__global__ void __launch_bounds__(256) k_compute_p(const float* __restrict__ x,
                                                   const void* __restrict__ u,
                                                   float* __restrict__ p,
                                                   const int* __restrict__ flags) {
    int f32 = flags[0];
    int wave = (blockIdx.x * blockDim.x + threadIdx.x) >> 6;
    int lane = threadIdx.x & 63;
    if (wave >= NN) return;
    float acc[HH] = {0, 0, 0, 0, 0, 0};
    for (int m = lane; m < CIN; m += 64) {
        float xv = x[(size_t)wave * CIN + m];
#pragma unroll
        for (int h = 0; h < HH; h++) acc[h] += xv * ldf(u, m * HH + h, f32);
    }
#pragma unroll
    for (int off = 32; off > 0; off >>= 1) {
#pragma unroll
        for (int h = 0; h < HH; h++) acc[h] += __shfl_down(acc[h], off, 64);
    }
    if (lane == 0) {
#pragma unroll
        for (int h = 0; h < HH; h++) p[(size_t)wave * HH + h] = acc[h];
    }
}

// ---------------- q = softmax(p[src]-p[dst]+c), in CSR slot order ----------------
__global__ void k_softmax_q(const int* __restrict__ ssrc, const int* __restrict__ sdst,
                            const float* __restrict__ p, const void* __restrict__ c,
                            float* __restrict__ q, const int* __restrict__ flags) {
    int f32 = flags[0];
    int e = blockIdx.x * blockDim.x + threadIdx.x;
    if (e >= NE) return;
    int s = ssrc[e], d = sdst[e];
    float t[HH];
    float mx = -1e30f;
#pragma unroll
    for (int h = 0; h < HH; h++) {
        t[h] = p[(size_t)s * HH + h] - p[(size_t)d * HH + h] + ldf(c, h, f32);
        mx = fmaxf(mx, t[h]);
    }
    float sum = 0.f;
#pragma unroll
    for (int h = 0; h < HH; h++) {
        t[h] = __expf(t[h] - mx);
        sum += t[h];
    }
    float inv = 1.0f / sum;
#pragma unroll
    for (int h = 0; h < HH; h++) q[(size_t)e * HH + h] = t[h] * inv;
}

// ---------------- aggregation: Agg[i, h*CIN+k] = (1/cnt) sum_j q_h x_j[k] ----------------
template <int CIN>
__global__ void __launch_bounds__(256) k_aggregate(const float* __restrict__ x,
                                                   const float* __restrict__ q,
                                                   const int* __restrict__ ssrc,
                                                   const int* __restrict__ offsets,
                                                   float* __restrict__ agg) {
    int node = (blockIdx.x * blockDim.x + threadIdx.x) >> 6;
    int lane = threadIdx.x & 63;
    if (node >= NN) return;
    int s0 = offsets[node], s1 = offsets[node + 1];
    int deg = s1 - s0;
    float scale = 1.0f / (float)(deg > 0 ? deg : 1);
    if constexpr (CIN == 128) {
        float acc0[HH] = {}, acc1[HH] = {};
        for (int s = s0; s < s1; s++) {
            int j = ssrc[s];
            float x0 = x[(size_t)j * 128 + lane];
            float x1 = x[(size_t)j * 128 + 64 + lane];
            const float* qe = q + (size_t)s * HH;
#pragma unroll
            for (int h = 0; h < HH; h++) {
                float qh = qe[h];
                acc0[h] += qh * x0;
                acc1[h] += qh * x1;
            }
        }
        float* ar = agg + (size_t)node * (HH * 128);
#pragma unroll
        for (int h = 0; h < HH; h++) {
            ar[h * 128 + lane]      = acc0[h] * scale;
            ar[h * 128 + 64 + lane] = acc1[h] * scale;
        }
    } else {  // CIN == 6: lanes 0..35 cover (h,k)
        int h = lane / 6, k = lane - h * 6;
        float acc = 0.f;
        if (lane < 36) {
            for (int s = s0; s < s1; s++) {
                int j = ssrc[s];
                acc += q[(size_t)s * HH + h] * x[(size_t)j * 6 + k];
            }
            agg[(size_t)node * 36 + lane] = acc * scale;
        }
    }
}

// ---------------- repack W[k, h*COUT+f] -> Wstk[(h*CIN+k)*COUT + f] ----------------
template <int CIN, int COUT>
__global__ void k_repack_w(const void* __restrict__ W, float* __restrict__ wstk,
                           const int* __restrict__ flags) {
    int f32 = flags[0];
    int idx = blockIdx.x * blockDim.x + threadIdx.x;
    if (idx >= HH * CIN * COUT) return;
    int f = idx % COUT;
    int m = idx / COUT;
    int h = m / CIN, k = m - h * CIN;
    wstk[idx] = ldf(W, k * (HH * COUT) + h * COUT + f, f32);
}

// ---------------- C[M,128] = A[M,K] @ B[K,128] + bias (opt ReLU) ----------------
// Block tile 64x128, BK=16, 256 threads, 4x8 micro-tile per thread. fp32.
__global__ void __launch_bounds__(256) k_gemm(const float* __restrict__ A,
                                              const float* __restrict__ B,
                                              const void* __restrict__ bias,
                                              float* __restrict__ C, int M, int K, int relu,
                                              const int* __restrict__ flags) {
    int f32 = flags[0];
    __shared__ float As[16][68];
    __shared__ float Bs[16][128];
    int tid = threadIdx.x;
    int tx = tid & 15;
    int ty = tid >> 4;
    int bm = blockIdx.x * 64;
    int arow = tid >> 2, ak = (tid & 3) * 4;
    int brow = tid >> 4, bcol = (tid & 15) * 8;
    float acc[4][8] = {};
    for (int k0 = 0; k0 < K; k0 += 16) {
        float4 av = {0, 0, 0, 0};
        int gr = bm + arow;
        if (gr < M && (k0 + ak) < K) av = *(const float4*)(A + (size_t)gr * K + k0 + ak);
        As[ak + 0][arow] = av.x;
        As[ak + 1][arow] = av.y;
        As[ak + 2][arow] = av.z;
        As[ak + 3][arow] = av.w;
        float4 bv0 = {0, 0, 0, 0}, bv1 = {0, 0, 0, 0};
        if ((k0 + brow) < K) {
            const float* bp = B + (size_t)(k0 + brow) * 128 + bcol;
            bv0 = *(const float4*)bp;
            bv1 = *(const float4*)(bp + 4);
        }
        *(float4*)&Bs[brow][bcol]     = bv0;
        *(float4*)&Bs[brow][bcol + 4] = bv1;
        __syncthreads();
#pragma unroll
        for (int kk = 0; kk < 16; kk++) {
            float a_[4], b_[8];
#pragma unroll
            for (int j = 0; j < 4; j++) a_[j] = As[kk][ty * 4 + j];
#pragma unroll
            for (int j = 0; j < 8; j++) b_[j] = Bs[kk][tx * 8 + j];
#pragma unroll
            for (int i = 0; i < 4; i++)
#pragma unroll
                for (int j = 0; j < 8; j++) acc[i][j] = fmaf(a_[i], b_[j], acc[i][j]);
        }
        __syncthreads();
    }
#pragma unroll
    for (int i = 0; i < 4; i++) {
        int row = bm + ty * 4 + i;
        if (row >= M) continue;
#pragma unroll
        for (int j = 0; j < 8; j++) {
            int col = tx * 8 + j;
            float v = acc[i][j] + ldf(bias, col, f32);
            if (relu) v = fmaxf(v, 0.f);
            C[(size_t)row * 128 + col] = v;
        }
    }
}

// ---------------- final layer: out[i,0..2] = Agg[i,:768] @ Wstk4[768,3] + b ----------------
__global__ void __launch_bounds__(256) k_final(const float* __restrict__ agg,
                                               const float* __restrict__ wstk,
                                               const void* __restrict__ bias,
                                               void* __restrict__ out,
                                               const int* __restrict__ flags) {
    int f32 = flags[0];
    int node = (blockIdx.x * blockDim.x + threadIdx.x) >> 6;
    int lane = threadIdx.x & 63;
    if (node >= NN) return;
    float f0 = 0, f1 = 0, f2 = 0;
    const float* ar = agg + (size_t)node * 768;
#pragma unroll
    for (int it = 0; it < 12; it++) {
        int m = it * 64 + lane;
        float a = ar[m];
        f0 += a * wstk[m * 3 + 0];
        f1 += a * wstk[m * 3 + 1];
        f2 += a * wstk[m * 3 + 2];
    }
#pragma unroll
    for (int off = 32; off > 0; off >>= 1) {
        f0 += __shfl_down(f0, off, 64);
        f1 += __shfl_down(f1, off, 64);
        f2 += __shfl_down(f2, off, 64);
    }
    if (lane == 0) {
        float r0 = f0 + ldf(bias, 0, f32);
        float r1 = f1 + ldf(bias, 1, f32);
        float r2 = f2 + ldf(bias, 2, f32);
        if (f32) {
            float* o = (float*)out;
            o[(size_t)node * 3 + 0] = r0;
            o[(size_t)node * 3 + 1] = r1;
            o[(size_t)node * 3 + 2] = r2;
        } else {
            __hip_bfloat16* o = (__hip_bfloat16*)out;
            o[(size_t)node * 3 + 0] = __float2bfloat16(r0);
            o[(size_t)node * 3 + 1] = __float2bfloat16(r1);
            o[(size_t)node * 3 + 2] = __float2bfloat16(r2);
        }
    }
}

extern "C" void kernel_launch(void* const* d_in, const int* in_sizes, int n_in,
                              void* d_out, int out_size, void* d_ws, size_t ws_size,
                              hipStream_t stream) {
    (void)in_sizes; (void)n_in; (void)out_size; (void)ws_size;
    const void* pos = d_in[0];
    const void* nrm = d_in[1];
    const int* ei = (const int*)d_in[2];
    const void* W[4] = {d_in[3], d_in[7], d_in[11], d_in[15]};
    const void* U[4] = {d_in[4], d_in[8], d_in[12], d_in[16]};
    const void* Cc[4] = {d_in[5], d_in[9], d_in[13], d_in[17]};
    const void* Bb[4] = {d_in[6], d_in[10], d_in[14], d_in[18]};

    // workspace carve-up (~258 MB total)
    char* wp = (char*)d_ws;
    auto alloc = [&](size_t b) { void* r = (void*)wp; wp += (b + 255) & ~(size_t)255; return r; };
    float* xA     = (float*)alloc((size_t)NN * 128 * 4);
    float* xB     = (float*)alloc((size_t)NN * 128 * 4);
    float* p      = (float*)alloc((size_t)NN * HH * 4);
    int*   counts = (int*)alloc((size_t)NN * 4);
    int*   offs   = (int*)alloc((size_t)(NN + 1) * 4);
    int*   cursor = (int*)alloc((size_t)NN * 4);
    int*   flags  = (int*)alloc(256);
    int*   ssrc   = (int*)alloc((size_t)NE * 4);
    int*   sdst   = (int*)alloc((size_t)NE * 4);
    float* qb     = (float*)alloc((size_t)NE * HH * 4);
    float* agg    = (float*)alloc((size_t)NN * 768 * 4);
    float* wstk   = (float*)alloc((size_t)768 * 128 * 4);

    const int EB = (NE + 255) / 256;
    const int NB = (NN + 255) / 256;
    const int NWB = (NN * 64 + 255) / 256;
    const int GB = (NN + 63) / 64;

    k_detect<<<1, 256, 0, stream>>>(pos, ei, flags);
    hipMemsetAsync(counts, 0, (size_t)NN * 4, stream);
    hipMemsetAsync(cursor, 0, (size_t)NN * 4, stream);
    k_count<<<EB, 256, 0, stream>>>(ei, counts, flags);
    k_scan<<<1, 1024, 0, stream>>>(counts, offs);
    k_scatter<<<EB, 256, 0, stream>>>(ei, offs, cursor, ssrc, sdst, flags);
    k_build_x0<<<NB, 256, 0, stream>>>(pos, nrm, xA, flags);

    // ---- layer 1: 6 -> 128, relu ----
    k_compute_p<6><<<NWB, 256, 0, stream>>>(xA, U[0], p, flags);
    k_softmax_q<<<EB, 256, 0, stream>>>(ssrc, sdst, p, Cc[0], qb, flags);
    k_aggregate<6><<<NWB, 256, 0, stream>>>(xA, qb, ssrc, offs, agg);
    k_repack_w<6, 128><<<(HH * 6 * 128 + 255) / 256, 256, 0, stream>>>(W[0], wstk, flags);
    k_gemm<<<GB, 256, 0, stream>>>(agg, wstk, Bb[0], xB, NN, 36, 1, flags);

    // ---- layer 2: 128 -> 128, relu ----
    k_compute_p<128><<<NWB, 256, 0, stream>>>(xB, U[1], p, flags);
    k_softmax_q<<<EB, 256, 0, stream>>>(ssrc, sdst, p, Cc[1], qb, flags);
    k_aggregate<128><<<NWB, 256, 0, stream>>>(xB, qb, ssrc, offs, agg);
    k_repack_w<128, 128><<<(HH * 128 * 128 + 255) / 256, 256, 0, stream>>>(W[1], wstk, flags);
    k_gemm<<<GB, 256, 0, stream>>>(agg, wstk, Bb[1], xA, NN, 768, 1, flags);

    // ---- layer 3: 128 -> 128, relu ----
    k_compute_p<128><<<NWB, 256, 0, stream>>>(xA, U[2], p, flags);
    k_softmax_q<<<EB, 256, 0, stream>>>(ssrc, sdst, p, Cc[2], qb, flags);
    k_aggregate<128><<<NWB, 256, 0, stream>>>(xA, qb, ssrc, offs, agg);
    k_repack_w<128, 128><<<(HH * 128 * 128 + 255) / 256, 256, 0, stream>>>(W[2], wstk, flags);
    k_gemm<<<GB, 256, 0, stream>>>(agg, wstk, Bb[2], xB, NN, 768, 1, flags);

    // ---- layer 4: 128 -> 3, no relu ----
    k_compute_p<128><<<NWB, 256, 0, stream>>>(xB, U[3], p, flags);
    k_softmax_q<<<EB, 256, 0, stream>>>(ssrc, sdst, p, Cc[3], qb, flags);
    k_aggregate<128><<<NWB, 256, 0, stream>>>(xB, qb, ssrc, offs, agg);
    k_repack_w<128, 3><<<(HH * 128 * 3 + 255) / 256, 256, 0, stream>>>(W[3], wstk, flags);
    k_final<<<NWB, 256, 0, stream>>>(agg, wstk, Bb[3], d_out, flags);
}

// Round 3
// 1315.761 us; speedup vs baseline: 1.1821x; 1.1821x over previous
//
#include <hip/hip_runtime.h>
#include <hip/hip_bf16.h>

// FeaStConv x4 on MI355X.
//  (1) (xj-xi)@u = p[src]-p[dst] with p = x@u per node.
//  (2) out_i = sum_h (sum_j q_h x_j) @ W_h  -> gather x_j into per-head
//      aggregates Agg[N, H*Cin], then ONE dense GEMM per layer.
// Round 3: node features x + aggregates stored bf16 (halves gather/write
// bytes); K=768 GEMMs use mfma_f32_16x16x32_bf16 w/ fp32 accumulate.
// q + p + all accumulation stay fp32.

#define HH 6
constexpr int NN = 50000;
constexpr int NE = 1600000;

typedef __attribute__((ext_vector_type(8))) short bf16x8;
typedef __attribute__((ext_vector_type(4))) float f32x4;

static __device__ __forceinline__ float b2f(__hip_bfloat16 v) { return __bfloat162float(v); }
static __device__ __forceinline__ float u2f(unsigned short u) {
    unsigned int x = ((unsigned int)u) << 16;
    return __uint_as_float(x);
}
static __device__ __forceinline__ unsigned short f2bu(float v) {
    __hip_bfloat16 b = __float2bfloat16(v);
    return *reinterpret_cast<unsigned short*>(&b);
}

// dual-dtype float load: f32 ? fp32[i] : bf16[i]
static __device__ __forceinline__ float ldf(const void* p, int i, int f32) {
    return f32 ? ((const float*)p)[i] : b2f(((const __hip_bfloat16*)p)[i]);
}
// dual-dtype edge-index load (element index i in the logical [2*NE] array)
static __device__ __forceinline__ int ldi(const int* e32, int i, int i64) {
    return i64 ? e32[2 * i] : e32[i];
}

// ---------------- dtype detection ----------------
__global__ void k_detect(const void* pos, const void* ei, int* flags) {
    __shared__ float smax[256];
    __shared__ int anynz;
    int t = threadIdx.x;
    if (t == 0) anynz = 0;
    const __hip_bfloat16* pb = (const __hip_bfloat16*)pos;
    float m = 0.f;
    for (int i = t; i < 2048; i += 256) {
        float v = fabsf(b2f(pb[i]));
        if (v != v) v = 1e30f;
        m = fmaxf(m, v);
    }
    smax[t] = m;
    __syncthreads();
    for (int s = 128; s > 0; s >>= 1) {
        if (t < s) smax[t] = fmaxf(smax[t], smax[t + s]);
        __syncthreads();
    }
    const int* e32 = (const int*)ei;
    if (t < 128 && e32[2 * t + 1] != 0) anynz = 1;
    __syncthreads();
    if (t == 0) {
        flags[0] = (smax[0] > 1e6f) ? 1 : 0;
        flags[1] = anynz ? 0 : 1;
    }
}

// ---------------- input assembly (x0 fp32 [N,6]) ----------------
__global__ void k_build_x0(const void* __restrict__ pos, const void* __restrict__ nrm,
                           float* __restrict__ x, const int* __restrict__ flags) {
    int f32 = flags[0];
    int i = blockIdx.x * blockDim.x + threadIdx.x;
    if (i >= NN) return;
#pragma unroll
    for (int j = 0; j < 3; j++) {
        x[i * 6 + j]     = ldf(pos, i * 3 + j, f32);
        x[i * 6 + 3 + j] = ldf(nrm, i * 3 + j, f32);
    }
}

// ---------------- CSR build (by dst) ----------------
__global__ void k_count(const int* __restrict__ ei, int* __restrict__ counts,
                        const int* __restrict__ flags) {
    int i64 = flags[1];
    int e = blockIdx.x * blockDim.x + threadIdx.x;
    if (e >= NE) return;
    atomicAdd(&counts[ldi(ei, NE + e, i64)], 1);
}

__global__ void __launch_bounds__(1024) k_scan(const int* __restrict__ counts,
                                               int* __restrict__ offsets) {
    __shared__ int wsum[16];
    __shared__ int s_running;
    int t = threadIdx.x;
    int lane = t & 63, wid = t >> 6;
    if (t == 0) s_running = 0;
    __syncthreads();
    for (int base = 0; base < NN; base += 1024) {
        int v = (base + t < NN) ? counts[base + t] : 0;
        int incl = v;
#pragma unroll
        for (int off = 1; off < 64; off <<= 1) {
            int n = __shfl_up(incl, off, 64);
            if (lane >= off) incl += n;
        }
        if (lane == 63) wsum[wid] = incl;
        __syncthreads();
        int wprefix = 0, total = 0;
#pragma unroll
        for (int wi = 0; wi < 16; wi++) {
            int s = wsum[wi];
            if (wi < wid) wprefix += s;
            total += s;
        }
        if (base + t < NN) offsets[base + t] = s_running + wprefix + (incl - v);
        __syncthreads();
        if (t == 0) s_running += total;
        __syncthreads();
    }
    if (t == 0) offsets[NN] = s_running;
}

__global__ void k_scatter(const int* __restrict__ ei, const int* __restrict__ offsets,
                          int* __restrict__ cursor, int* __restrict__ ssrc,
                          int* __restrict__ sdst, const int* __restrict__ flags) {
    int i64 = flags[1];
    int e = blockIdx.x * blockDim.x + threadIdx.x;
    if (e >= NE) return;
    int s = ldi(ei, e, i64), d = ldi(ei, NE + e, i64);
    int slot = offsets[d] + atomicAdd(&cursor[d], 1);
    ssrc[slot] = s;
    sdst[slot] = d;
}

// ---------------- p = x @ u ----------------
// layer 1: x fp32 [N,6]
__global__ void __launch_bounds__(256) k_compute_p6(const float* __restrict__ x,
                                                    const void* __restrict__ u,
                                                    float* __restrict__ p,
                                                    const int* __restrict__ flags) {
    int f32 = flags[0];
    int wave = (blockIdx.x * blockDim.x + threadIdx.x) >> 6;
    int lane = threadIdx.x & 63;
    if (wave >= NN) return;
    float acc[HH] = {0, 0, 0, 0, 0, 0};
    if (lane < 6) {
        float xv = x[(size_t)wave * 6 + lane];
#pragma unroll
        for (int h = 0; h < HH; h++) acc[h] = xv * ldf(u, lane * HH + h, f32);
    }
#pragma unroll
    for (int off = 4; off > 0; off >>= 1) {
#pragma unroll
        for (int h = 0; h < HH; h++) acc[h] += __shfl_down(acc[h], off, 64);
    }
    if (lane == 0) {
#pragma unroll
        for (int h = 0; h < HH; h++) p[(size_t)wave * HH + h] = acc[h];
    }
}

// layers 2-4: x bf16 [N,128], lane covers channels 2l, 2l+1
__global__ void __launch_bounds__(256) k_compute_p128(const unsigned short* __restrict__ x,
                                                      const void* __restrict__ u,
                                                      float* __restrict__ p,
                                                      const int* __restrict__ flags) {
    int f32 = flags[0];
    int wave = (blockIdx.x * blockDim.x + threadIdx.x) >> 6;
    int lane = threadIdx.x & 63;
    if (wave >= NN) return;
    unsigned int w = *(const unsigned int*)(x + (size_t)wave * 128 + 2 * lane);
    float x0 = u2f((unsigned short)(w & 0xffff));
    float x1 = u2f((unsigned short)(w >> 16));
    float acc[HH];
#pragma unroll
    for (int h = 0; h < HH; h++)
        acc[h] = x0 * ldf(u, (2 * lane) * HH + h, f32) + x1 * ldf(u, (2 * lane + 1) * HH + h, f32);
#pragma unroll
    for (int off = 32; off > 0; off >>= 1) {
#pragma unroll
        for (int h = 0; h < HH; h++) acc[h] += __shfl_down(acc[h], off, 64);
    }
    if (lane == 0) {
#pragma unroll
        for (int h = 0; h < HH; h++) p[(size_t)wave * HH + h] = acc[h];
    }
}

// ---------------- q = softmax(p[src]-p[dst]+c) ----------------
__global__ void k_softmax_q(const int* __restrict__ ssrc, const int* __restrict__ sdst,
                            const float* __restrict__ p, const void* __restrict__ c,
                            float* __restrict__ q, const int* __restrict__ flags) {
    int f32 = flags[0];
    int e = blockIdx.x * blockDim.x + threadIdx.x;
    if (e >= NE) return;
    int s = ssrc[e], d = sdst[e];
    float t[HH];
    float mx = -1e30f;
#pragma unroll
    for (int h = 0; h < HH; h++) {
        t[h] = p[(size_t)s * HH + h] - p[(size_t)d * HH + h] + ldf(c, h, f32);
        mx = fmaxf(mx, t[h]);
    }
    float sum = 0.f;
#pragma unroll
    for (int h = 0; h < HH; h++) {
        t[h] = __expf(t[h] - mx);
        sum += t[h];
    }
    float inv = 1.0f / sum;
#pragma unroll
    for (int h = 0; h < HH; h++) q[(size_t)e * HH + h] = t[h] * inv;
}

// ---------------- aggregation ----------------
// layer 1: x fp32 [N,6] -> agg fp32 [N,36]
__global__ void __launch_bounds__(256) k_aggregate6(const float* __restrict__ x,
                                                    const float* __restrict__ q,
                                                    const int* __restrict__ ssrc,
                                                    const int* __restrict__ offsets,
                                                    float* __restrict__ agg) {
    int node = (blockIdx.x * blockDim.x + threadIdx.x) >> 6;
    int lane = threadIdx.x & 63;
    if (node >= NN) return;
    int s0 = offsets[node], s1 = offsets[node + 1];
    int deg = s1 - s0;
    float scale = 1.0f / (float)(deg > 0 ? deg : 1);
    int h = lane / 6, k = lane - h * 6;
    float acc = 0.f;
    if (lane < 36) {
        for (int s = s0; s < s1; s++) {
            int j = ssrc[s];
            acc += q[(size_t)s * HH + h] * x[(size_t)j * 6 + k];
        }
        agg[(size_t)node * 36 + lane] = acc * scale;
    }
}

// layers 2-4: x bf16 [N,128] -> agg bf16 [N,768]; lane covers channels 2l,2l+1
__global__ void __launch_bounds__(256) k_aggregate128(const unsigned short* __restrict__ x,
                                                      const float* __restrict__ q,
                                                      const int* __restrict__ ssrc,
                                                      const int* __restrict__ offsets,
                                                      unsigned short* __restrict__ agg) {
    int node = (blockIdx.x * blockDim.x + threadIdx.x) >> 6;
    int lane = threadIdx.x & 63;
    if (node >= NN) return;
    int s0 = offsets[node], s1 = offsets[node + 1];
    int deg = s1 - s0;
    float scale = 1.0f / (float)(deg > 0 ? deg : 1);
    float a0[HH] = {}, a1[HH] = {};
    for (int s = s0; s < s1; s++) {
        int j = ssrc[s];
        unsigned int w = *(const unsigned int*)(x + (size_t)j * 128 + 2 * lane);
        float x0 = u2f((unsigned short)(w & 0xffff));
        float x1 = u2f((unsigned short)(w >> 16));
        const float* qe = q + (size_t)s * HH;
#pragma unroll
        for (int h = 0; h < HH; h++) {
            float qh = qe[h];
            a0[h] += qh * x0;
            a1[h] += qh * x1;
        }
    }
    unsigned short* ar = agg + (size_t)node * 768;
#pragma unroll
    for (int h = 0; h < HH; h++) {
        unsigned int wv = ((unsigned int)f2bu(a1[h] * scale) << 16) | f2bu(a0[h] * scale);
        *(unsigned int*)(ar + h * 128 + 2 * lane) = wv;
    }
}

// ---------------- weight repacks ----------------
// fp32 Wstk[(h*CIN+k)*COUT + f] for layer-1 gemm / layer-4 gemv
template <int CIN, int COUT>
__global__ void k_repack_w(const void* __restrict__ W, float* __restrict__ wstk,
                           const int* __restrict__ flags) {
    int f32 = flags[0];
    int idx = blockIdx.x * blockDim.x + threadIdx.x;
    if (idx >= HH * CIN * COUT) return;
    int f = idx % COUT;
    int m = idx / COUT;
    int h = m / CIN, k = m - h * CIN;
    wstk[idx] = ldf(W, k * (HH * COUT) + h * COUT + f, f32);
}

// bf16 Wt[n][h*128+kk] = W[kk][h*128+n]  (B^T for MFMA GEMM), n<128, K=768
__global__ void k_repack_wt(const void* __restrict__ W, unsigned short* __restrict__ wt,
                            const int* __restrict__ flags) {
    int f32 = flags[0];
    int idx = blockIdx.x * blockDim.x + threadIdx.x;
    if (idx >= 128 * 768) return;
    int f = idx / 768;             // output channel n
    int m = idx % 768;             // k index: h*128 + kk
    int h = m >> 7, kk = m & 127;
    wt[idx] = f2bu(ldf(W, kk * 768 + h * 128 + f, f32));
}

// ---------------- layer-1 GEMM (fp32, K=36), writes bf16 x ----------------
__global__ void __launch_bounds__(256) k_gemm_f32(const float* __restrict__ A,
                                                  const float* __restrict__ B,
                                                  const void* __restrict__ bias,
                                                  unsigned short* __restrict__ C,
                                                  int M, int K, int relu,
                                                  const int* __restrict__ flags) {
    int f32 = flags[0];
    __shared__ float As[16][68];
    __shared__ float Bs[16][128];
    int tid = threadIdx.x;
    int tx = tid & 15;
    int ty = tid >> 4;
    int bm = blockIdx.x * 64;
    int arow = tid >> 2, ak = (tid & 3) * 4;
    int brow = tid >> 4, bcol = (tid & 15) * 8;
    float acc[4][8] = {};
    for (int k0 = 0; k0 < K; k0 += 16) {
        float4 av = {0, 0, 0, 0};
        int gr = bm + arow;
        if (gr < M && (k0 + ak) < K) av = *(const float4*)(A + (size_t)gr * K + k0 + ak);
        As[ak + 0][arow] = av.x;
        As[ak + 1][arow] = av.y;
        As[ak + 2][arow] = av.z;
        As[ak + 3][arow] = av.w;
        float4 bv0 = {0, 0, 0, 0}, bv1 = {0, 0, 0, 0};
        if ((k0 + brow) < K) {
            const float* bp = B + (size_t)(k0 + brow) * 128 + bcol;
            bv0 = *(const float4*)bp;
            bv1 = *(const float4*)(bp + 4);
        }
        *(float4*)&Bs[brow][bcol]     = bv0;
        *(float4*)&Bs[brow][bcol + 4] = bv1;
        __syncthreads();
#pragma unroll
        for (int kk = 0; kk < 16; kk++) {
            float a_[4], b_[8];
#pragma unroll
            for (int j = 0; j < 4; j++) a_[j] = As[kk][ty * 4 + j];
#pragma unroll
            for (int j = 0; j < 8; j++) b_[j] = Bs[kk][tx * 8 + j];
#pragma unroll
            for (int i = 0; i < 4; i++)
#pragma unroll
                for (int j = 0; j < 8; j++) acc[i][j] = fmaf(a_[i], b_[j], acc[i][j]);
        }
        __syncthreads();
    }
#pragma unroll
    for (int i = 0; i < 4; i++) {
        int row = bm + ty * 4 + i;
        if (row >= M) continue;
#pragma unroll
        for (int j = 0; j < 8; j++) {
            int col = tx * 8 + j;
            float v = acc[i][j] + ldf(bias, col, f32);
            if (relu) v = fmaxf(v, 0.f);
            C[(size_t)row * 128 + col] = f2bu(v);
        }
    }
}

// ---------------- MFMA GEMM: C[M,128] = A[M,768]bf16 @ Wt^T + bias, ReLU ----
// 64x128 block tile, BK=64, 256 threads = 4 waves (2x2), wave tile 32x64.
__global__ void __launch_bounds__(256) k_gemm_mfma(const unsigned short* __restrict__ A,
                                                   const unsigned short* __restrict__ Bt,
                                                   const void* __restrict__ bias,
                                                   unsigned short* __restrict__ C,
                                                   int M, int relu,
                                                   const int* __restrict__ flags) {
    constexpr int K = 768, BK = 64;
    __shared__ unsigned short As[64][72];   // +8 pad: row stride 144B = 36 dwords
    __shared__ unsigned short Bs[128][72];
    int f32 = flags[0];
    int tid = threadIdx.x;
    int lane = tid & 63, wid = tid >> 6;
    int wm = wid & 1, wn = wid >> 1;        // wave (wm,wn): rows wm*32.., cols wn*64..
    int bm = blockIdx.x * 64;
    int l15 = lane & 15, lq = lane >> 4;    // quad id 0..3
    f32x4 acc[2][4] = {};                    // [tm][tn]

    for (int k0 = 0; k0 < K; k0 += BK) {
        // stage A: 64 rows x 64 k (each thread 2 chunks of 8 bf16)
#pragma unroll
        for (int cc = 0; cc < 2; cc++) {
            int c = tid + cc * 256;
            int r = c >> 3, kc = (c & 7) * 8;
            bf16x8 av = {};
            int gr = bm + r;
            if (gr < M) av = *(const bf16x8*)(A + (size_t)gr * K + k0 + kc);
            *(bf16x8*)&As[r][kc] = av;
        }
        // stage Bt: 128 rows(n) x 64 k (each thread 4 chunks)
#pragma unroll
        for (int cc = 0; cc < 4; cc++) {
            int c = tid + cc * 256;
            int n = c >> 3, kc = (c & 7) * 8;
            *(bf16x8*)&Bs[n][kc] = *(const bf16x8*)(Bt + (size_t)n * K + k0 + kc);
        }
        __syncthreads();
#pragma unroll
        for (int ks = 0; ks < BK; ks += 32) {
            int koff = ks + lq * 8;
            bf16x8 af[2], bf[4];
#pragma unroll
            for (int tm = 0; tm < 2; tm++)
                af[tm] = *(const bf16x8*)&As[wm * 32 + tm * 16 + l15][koff];
#pragma unroll
            for (int tn = 0; tn < 4; tn++)
                bf[tn] = *(const bf16x8*)&Bs[wn * 64 + tn * 16 + l15][koff];
#pragma unroll
            for (int tm = 0; tm < 2; tm++)
#pragma unroll
                for (int tn = 0; tn < 4; tn++)
                    acc[tm][tn] = __builtin_amdgcn_mfma_f32_16x16x32_bf16(
                        af[tm], bf[tn], acc[tm][tn], 0, 0, 0);
        }
        __syncthreads();
    }
    // epilogue: C[row = bm + wm*32 + tm*16 + lq*4 + r][col = wn*64 + tn*16 + l15]
#pragma unroll
    for (int tm = 0; tm < 2; tm++) {
#pragma unroll
        for (int tn = 0; tn < 4; tn++) {
            int col = wn * 64 + tn * 16 + l15;
            float bv = ldf(bias, col, f32);
#pragma unroll
            for (int r = 0; r < 4; r++) {
                int row = bm + wm * 32 + tm * 16 + lq * 4 + r;
                if (row < M) {
                    float v = acc[tm][tn][r] + bv;
                    if (relu) v = fmaxf(v, 0.f);
                    C[(size_t)row * 128 + col] = f2bu(v);
                }
            }
        }
    }
}

// ---------------- final layer: out[i,0..2] = Agg_bf16[i,:768] @ Wstk4[768,3] + b ----
__global__ void __launch_bounds__(256) k_final(const unsigned short* __restrict__ agg,
                                               const float* __restrict__ wstk,
                                               const void* __restrict__ bias,
                                               void* __restrict__ out,
                                               const int* __restrict__ flags) {
    int f32 = flags[0];
    int node = (blockIdx.x * blockDim.x + threadIdx.x) >> 6;
    int lane = threadIdx.x & 63;
    if (node >= NN) return;
    float f0 = 0, f1 = 0, f2 = 0;
    const unsigned short* ar = agg + (size_t)node * 768;
#pragma unroll
    for (int it = 0; it < 6; it++) {
        int m = it * 128 + 2 * lane;
        unsigned int w = *(const unsigned int*)(ar + m);
        float a0 = u2f((unsigned short)(w & 0xffff));
        float a1 = u2f((unsigned short)(w >> 16));
        f0 += a0 * wstk[m * 3 + 0] + a1 * wstk[m * 3 + 3];
        f1 += a0 * wstk[m * 3 + 1] + a1 * wstk[m * 3 + 4];
        f2 += a0 * wstk[m * 3 + 2] + a1 * wstk[m * 3 + 5];
    }
#pragma unroll
    for (int off = 32; off > 0; off >>= 1) {
        f0 += __shfl_down(f0, off, 64);
        f1 += __shfl_down(f1, off, 64);
        f2 += __shfl_down(f2, off, 64);
    }
    if (lane == 0) {
        float r0 = f0 + ldf(bias, 0, f32);
        float r1 = f1 + ldf(bias, 1, f32);
        float r2 = f2 + ldf(bias, 2, f32);
        if (f32) {
            float* o = (float*)out;
            o[(size_t)node * 3 + 0] = r0;
            o[(size_t)node * 3 + 1] = r1;
            o[(size_t)node * 3 + 2] = r2;
        } else {
            __hip_bfloat16* o = (__hip_bfloat16*)out;
            o[(size_t)node * 3 + 0] = __float2bfloat16(r0);
            o[(size_t)node * 3 + 1] = __float2bfloat16(r1);
            o[(size_t)node * 3 + 2] = __float2bfloat16(r2);
        }
    }
}

extern "C" void kernel_launch(void* const* d_in, const int* in_sizes, int n_in,
                              void* d_out, int out_size, void* d_ws, size_t ws_size,
                              hipStream_t stream) {
    (void)in_sizes; (void)n_in; (void)out_size; (void)ws_size;
    const void* pos = d_in[0];
    const void* nrm = d_in[1];
    const int* ei = (const int*)d_in[2];
    const void* W[4] = {d_in[3], d_in[7], d_in[11], d_in[15]};
    const void* U[4] = {d_in[4], d_in[8], d_in[12], d_in[16]};
    const void* Cc[4] = {d_in[5], d_in[9], d_in[13], d_in[17]};
    const void* Bb[4] = {d_in[6], d_in[10], d_in[14], d_in[18]};

    // workspace carve-up (~160 MB total)
    char* wp = (char*)d_ws;
    auto alloc = [&](size_t b) { void* r = (void*)wp; wp += (b + 255) & ~(size_t)255; return r; };
    unsigned short* xA = (unsigned short*)alloc((size_t)NN * 128 * 2);  // bf16
    unsigned short* xB = (unsigned short*)alloc((size_t)NN * 128 * 2);  // bf16
    float* x0     = (float*)alloc((size_t)NN * 6 * 4);
    float* p      = (float*)alloc((size_t)NN * HH * 4);
    int*   counts = (int*)alloc((size_t)NN * 4);
    int*   offs   = (int*)alloc((size_t)(NN + 1) * 4);
    int*   cursor = (int*)alloc((size_t)NN * 4);
    int*   flags  = (int*)alloc(256);
    int*   ssrc   = (int*)alloc((size_t)NE * 4);
    int*   sdst   = (int*)alloc((size_t)NE * 4);
    float* qb     = (float*)alloc((size_t)NE * HH * 4);
    void*  aggv   = alloc((size_t)NN * 768 * 2);      // bf16 [N,768] or fp32 [N,36]
    float* wstk_f = (float*)alloc((size_t)768 * 128 * 4);
    unsigned short* wt = (unsigned short*)alloc((size_t)128 * 768 * 2);
    unsigned short* agg_h = (unsigned short*)aggv;
    float* agg_f = (float*)aggv;

    const int EB = (NE + 255) / 256;
    const int NB = (NN + 255) / 256;
    const int NWB = (NN * 64 + 255) / 256;
    const int GB = (NN + 63) / 64;

    k_detect<<<1, 256, 0, stream>>>(pos, ei, flags);
    hipMemsetAsync(counts, 0, (size_t)NN * 4, stream);
    hipMemsetAsync(cursor, 0, (size_t)NN * 4, stream);
    k_count<<<EB, 256, 0, stream>>>(ei, counts, flags);
    k_scan<<<1, 1024, 0, stream>>>(counts, offs);
    k_scatter<<<EB, 256, 0, stream>>>(ei, offs, cursor, ssrc, sdst, flags);
    k_build_x0<<<NB, 256, 0, stream>>>(pos, nrm, x0, flags);

    // ---- layer 1: 6 -> 128, relu (fp32 path, bf16 output) ----
    k_compute_p6<<<NWB, 256, 0, stream>>>(x0, U[0], p, flags);
    k_softmax_q<<<EB, 256, 0, stream>>>(ssrc, sdst, p, Cc[0], qb, flags);
    k_aggregate6<<<NWB, 256, 0, stream>>>(x0, qb, ssrc, offs, agg_f);
    k_repack_w<6, 128><<<(HH * 6 * 128 + 255) / 256, 256, 0, stream>>>(W[0], wstk_f, flags);
    k_gemm_f32<<<GB, 256, 0, stream>>>(agg_f, wstk_f, Bb[0], xA, NN, 36, 1, flags);

    // ---- layer 2: 128 -> 128, relu (bf16 + MFMA) ----
    k_compute_p128<<<NWB, 256, 0, stream>>>(xA, U[1], p, flags);
    k_softmax_q<<<EB, 256, 0, stream>>>(ssrc, sdst, p, Cc[1], qb, flags);
    k_aggregate128<<<NWB, 256, 0, stream>>>(xA, qb, ssrc, offs, agg_h);
    k_repack_wt<<<(128 * 768 + 255) / 256, 256, 0, stream>>>(W[1], wt, flags);
    k_gemm_mfma<<<GB, 256, 0, stream>>>(agg_h, wt, Bb[1], xB, NN, 1, flags);

    // ---- layer 3: 128 -> 128, relu ----
    k_compute_p128<<<NWB, 256, 0, stream>>>(xB, U[2], p, flags);
    k_softmax_q<<<EB, 256, 0, stream>>>(ssrc, sdst, p, Cc[2], qb, flags);
    k_aggregate128<<<NWB, 256, 0, stream>>>(xB, qb, ssrc, offs, agg_h);
    k_repack_wt<<<(128 * 768 + 255) / 256, 256, 0, stream>>>(W[2], wt, flags);
    k_gemm_mfma<<<GB, 256, 0, stream>>>(agg_h, wt, Bb[2], xA, NN, 1, flags);

    // ---- layer 4: 128 -> 3 ----
    k_compute_p128<<<NWB, 256, 0, stream>>>(xA, U[3], p, flags);
    k_softmax_q<<<EB, 256, 0, stream>>>(ssrc, sdst, p, Cc[3], qb, flags);
    k_aggregate128<<<NWB, 256, 0, stream>>>(xA, qb, ssrc, offs, agg_h);
    k_repack_w<128, 3><<<(HH * 128 * 3 + 255) / 256, 256, 0, stream>>>(W[3], wstk_f, flags);
    k_final<<<NWB, 256, 0, stream>>>(agg_h, wstk_f, Bb[3], d_out, flags);
}

// Round 4
// 837.765 us; speedup vs baseline: 1.8565x; 1.5706x over previous
//
#include <hip/hip_runtime.h>
#include <hip/hip_bf16.h>

// FeaStConv x4 on MI355X.
//  (1) (xj-xi)@u = p[src]-p[dst] with p = x@u per node (p padded to [N,8]).
//  (2) out_i = sum_h (sum_j q_h x_j) @ W_h  -> gather x_j into per-head
//      aggregates Agg[N, H*Cin], then ONE dense GEMM per layer (MFMA bf16).
// Round 4: softmax FUSED into aggregation. Per 64-edge chunk: phase A
// (lane=edge) computes q -> one 16B LDS entry {q bf16 x6, j*ROW}; phase B
// (lane=channel) does ONE ds_read_b128 + ONE global dword gather per edge,
// unrolled x4 for ILP. Kills k_softmax_q + qb + sdst entirely.

#define HH 6
constexpr int NN = 50000;
constexpr int NE = 1600000;

typedef __attribute__((ext_vector_type(8))) short bf16x8;
typedef __attribute__((ext_vector_type(4))) float f32x4;

static __device__ __forceinline__ float b2f(__hip_bfloat16 v) { return __bfloat162float(v); }
static __device__ __forceinline__ float u2f(unsigned short u) {
    return __uint_as_float(((unsigned int)u) << 16);
}
static __device__ __forceinline__ unsigned short f2bu(float v) {
    __hip_bfloat16 b = __float2bfloat16(v);
    return *reinterpret_cast<unsigned short*>(&b);
}
static __device__ __forceinline__ float lo2f(unsigned int w) {
    return __uint_as_float(w << 16);
}
static __device__ __forceinline__ float hi2f(unsigned int w) {
    return __uint_as_float(w & 0xffff0000u);
}
static __device__ __forceinline__ unsigned int pk2(float lo, float hi) {
    return ((unsigned int)f2bu(hi) << 16) | (unsigned int)f2bu(lo);
}

// dual-dtype float load: f32 ? fp32[i] : bf16[i]
static __device__ __forceinline__ float ldf(const void* p, int i, int f32) {
    return f32 ? ((const float*)p)[i] : b2f(((const __hip_bfloat16*)p)[i]);
}
static __device__ __forceinline__ int ldi(const int* e32, int i, int i64) {
    return i64 ? e32[2 * i] : e32[i];
}

// ---------------- dtype detection ----------------
__global__ void k_detect(const void* pos, const void* ei, int* flags) {
    __shared__ float smax[256];
    __shared__ int anynz;
    int t = threadIdx.x;
    if (t == 0) anynz = 0;
    const __hip_bfloat16* pb = (const __hip_bfloat16*)pos;
    float m = 0.f;
    for (int i = t; i < 2048; i += 256) {
        float v = fabsf(b2f(pb[i]));
        if (v != v) v = 1e30f;
        m = fmaxf(m, v);
    }
    smax[t] = m;
    __syncthreads();
    for (int s = 128; s > 0; s >>= 1) {
        if (t < s) smax[t] = fmaxf(smax[t], smax[t + s]);
        __syncthreads();
    }
    const int* e32 = (const int*)ei;
    if (t < 128 && e32[2 * t + 1] != 0) anynz = 1;
    __syncthreads();
    if (t == 0) {
        flags[0] = (smax[0] > 1e6f) ? 1 : 0;
        flags[1] = anynz ? 0 : 1;
    }
}

// ---------------- input assembly: x0 bf16 [N,8] (pads 0) ----------------
__global__ void k_build_x0(const void* __restrict__ pos, const void* __restrict__ nrm,
                           unsigned short* __restrict__ x0b, const int* __restrict__ flags) {
    int f32 = flags[0];
    int i = blockIdx.x * blockDim.x + threadIdx.x;
    if (i >= NN) return;
#pragma unroll
    for (int j = 0; j < 3; j++) {
        x0b[i * 8 + j]     = f32 ? f2bu(((const float*)pos)[i * 3 + j])
                                 : ((const unsigned short*)pos)[i * 3 + j];
        x0b[i * 8 + 3 + j] = f32 ? f2bu(((const float*)nrm)[i * 3 + j])
                                 : ((const unsigned short*)nrm)[i * 3 + j];
    }
    x0b[i * 8 + 6] = 0;
    x0b[i * 8 + 7] = 0;
}

// ---------------- CSR build (by dst) ----------------
__global__ void k_count(const int* __restrict__ ei, int* __restrict__ counts,
                        const int* __restrict__ flags) {
    int i64 = flags[1];
    int e = blockIdx.x * blockDim.x + threadIdx.x;
    if (e >= NE) return;
    atomicAdd(&counts[ldi(ei, NE + e, i64)], 1);
}

__global__ void __launch_bounds__(1024) k_scan(const int* __restrict__ counts,
                                               int* __restrict__ offsets) {
    __shared__ int wsum[16];
    __shared__ int s_running;
    int t = threadIdx.x;
    int lane = t & 63, wid = t >> 6;
    if (t == 0) s_running = 0;
    __syncthreads();
    for (int base = 0; base < NN; base += 1024) {
        int v = (base + t < NN) ? counts[base + t] : 0;
        int incl = v;
#pragma unroll
        for (int off = 1; off < 64; off <<= 1) {
            int n = __shfl_up(incl, off, 64);
            if (lane >= off) incl += n;
        }
        if (lane == 63) wsum[wid] = incl;
        __syncthreads();
        int wprefix = 0, total = 0;
#pragma unroll
        for (int wi = 0; wi < 16; wi++) {
            int s = wsum[wi];
            if (wi < wid) wprefix += s;
            total += s;
        }
        if (base + t < NN) offsets[base + t] = s_running + wprefix + (incl - v);
        __syncthreads();
        if (t == 0) s_running += total;
        __syncthreads();
    }
    if (t == 0) offsets[NN] = s_running;
}

__global__ void k_scatter(const int* __restrict__ ei, const int* __restrict__ offsets,
                          int* __restrict__ cursor, int* __restrict__ ssrc,
                          const int* __restrict__ flags) {
    int i64 = flags[1];
    int e = blockIdx.x * blockDim.x + threadIdx.x;
    if (e >= NE) return;
    int s = ldi(ei, e, i64), d = ldi(ei, NE + e, i64);
    int slot = offsets[d] + atomicAdd(&cursor[d], 1);
    ssrc[slot] = s;
}

// ---------------- p = x @ u  ->  p8 [N,8] fp32 (h<6 valid) ----------------
// layer 1: x0 bf16 [N,8]
__global__ void __launch_bounds__(256) k_compute_p6(const unsigned short* __restrict__ x0b,
                                                    const void* __restrict__ u,
                                                    float* __restrict__ p8,
                                                    const int* __restrict__ flags) {
    int f32 = flags[0];
    int wave = (blockIdx.x * blockDim.x + threadIdx.x) >> 6;
    int lane = threadIdx.x & 63;
    if (wave >= NN) return;
    float acc[HH] = {0, 0, 0, 0, 0, 0};
    if (lane < 6) {
        float xv = u2f(x0b[(size_t)wave * 8 + lane]);
#pragma unroll
        for (int h = 0; h < HH; h++) acc[h] = xv * ldf(u, lane * HH + h, f32);
    }
#pragma unroll
    for (int off = 4; off > 0; off >>= 1) {
#pragma unroll
        for (int h = 0; h < HH; h++) acc[h] += __shfl_down(acc[h], off, 64);
    }
    if (lane == 0) {
#pragma unroll
        for (int h = 0; h < HH; h++) p8[(size_t)wave * 8 + h] = acc[h];
    }
}

// layers 2-4: x bf16 [N,128]
__global__ void __launch_bounds__(256) k_compute_p128(const unsigned short* __restrict__ x,
                                                      const void* __restrict__ u,
                                                      float* __restrict__ p8,
                                                      const int* __restrict__ flags) {
    int f32 = flags[0];
    int wave = (blockIdx.x * blockDim.x + threadIdx.x) >> 6;
    int lane = threadIdx.x & 63;
    if (wave >= NN) return;
    unsigned int w = *(const unsigned int*)(x + (size_t)wave * 128 + 2 * lane);
    float x0 = lo2f(w);
    float x1 = hi2f(w);
    float acc[HH];
#pragma unroll
    for (int h = 0; h < HH; h++)
        acc[h] = x0 * ldf(u, (2 * lane) * HH + h, f32) + x1 * ldf(u, (2 * lane + 1) * HH + h, f32);
#pragma unroll
    for (int off = 32; off > 0; off >>= 1) {
#pragma unroll
        for (int h = 0; h < HH; h++) acc[h] += __shfl_down(acc[h], off, 64);
    }
    if (lane == 0) {
#pragma unroll
        for (int h = 0; h < HH; h++) p8[(size_t)wave * 8 + h] = acc[h];
    }
}

// ---------------- fused softmax + aggregation ----------------
static __device__ __forceinline__ void edge_acc(uint4 ent, unsigned int xw,
                                                float* a0, float* a1) {
    float x0 = lo2f(xw), x1 = hi2f(xw);
    float q[6] = {lo2f(ent.x), hi2f(ent.x), lo2f(ent.y),
                  hi2f(ent.y), lo2f(ent.z), hi2f(ent.z)};
#pragma unroll
    for (int h = 0; h < HH; h++) {
        a0[h] += q[h] * x0;
        a1[h] += q[h] * x1;
    }
}

// CIN=128: agg bf16 [N,768].  CIN=6: agg fp32 [N,36].
template <int CIN>
__global__ void __launch_bounds__(256) k_agg_fused(const unsigned short* __restrict__ xb,
                                                   const float* __restrict__ p8,
                                                   const void* __restrict__ cvec,
                                                   const int* __restrict__ ssrc,
                                                   const int* __restrict__ offs,
                                                   void* __restrict__ aggv,
                                                   const int* __restrict__ flags) {
    constexpr int ROW = (CIN == 6) ? 8 : 128;
    __shared__ uint4 qs[4][64];
    int f32 = flags[0];
    int wid = threadIdx.x >> 6, lane = threadIdx.x & 63;
    int node = (blockIdx.x * blockDim.x + threadIdx.x) >> 6;
    if (node >= NN) return;
    int s0 = offs[node], s1 = offs[node + 1];
    int deg = s1 - s0;
    float scale = 1.0f / (float)(deg > 0 ? deg : 1);
    const float* pn = p8 + (size_t)node * 8;
    float pd[HH];
#pragma unroll
    for (int h = 0; h < HH; h++) pd[h] = pn[h] - ldf(cvec, h, f32);

    float a0[HH] = {}, a1[HH] = {};  // CIN=128 accumulators
    float acc6 = 0.f;                // CIN=6 accumulator
    int hh = lane / 6, kk = lane - hh * 6;
    int hc = hh < 6 ? hh : 5;        // clamped for inactive lanes

    for (int base = s0; base < s1; base += 64) {
        // ---- phase A: lane = edge; q -> 16B LDS entry ----
        int e = base + lane;
        int j = (e < s1) ? ssrc[e] : 0;
        const float* pj = p8 + (size_t)j * 8;
        float4 pa = *(const float4*)pj;
        float2 pb = *(const float2*)(pj + 4);
        float t0 = pa.x - pd[0], t1 = pa.y - pd[1], t2 = pa.z - pd[2];
        float t3 = pa.w - pd[3], t4 = pb.x - pd[4], t5 = pb.y - pd[5];
        float mx = fmaxf(fmaxf(fmaxf(t0, t1), fmaxf(t2, t3)), fmaxf(t4, t5));
        float q0 = __expf(t0 - mx), q1 = __expf(t1 - mx), q2 = __expf(t2 - mx);
        float q3 = __expf(t3 - mx), q4 = __expf(t4 - mx), q5 = __expf(t5 - mx);
        float inv = 1.0f / (q0 + q1 + q2 + q3 + q4 + q5);
        uint4 ent;
        ent.x = pk2(q0 * inv, q1 * inv);
        ent.y = pk2(q2 * inv, q3 * inv);
        ent.z = pk2(q4 * inv, q5 * inv);
        ent.w = (unsigned int)(j * ROW);
        qs[wid][lane] = ent;
        int cnt = (s1 - base < 64) ? (s1 - base) : 64;
        // ---- phase B: lane = channel ----
        if constexpr (CIN == 128) {
            int s = 0;
            for (; s + 4 <= cnt; s += 4) {
                uint4 e0 = qs[wid][s + 0];
                uint4 e1 = qs[wid][s + 1];
                uint4 e2 = qs[wid][s + 2];
                uint4 e3 = qs[wid][s + 3];
                unsigned int w0 = *(const unsigned int*)(xb + (size_t)e0.w + 2 * lane);
                unsigned int w1 = *(const unsigned int*)(xb + (size_t)e1.w + 2 * lane);
                unsigned int w2 = *(const unsigned int*)(xb + (size_t)e2.w + 2 * lane);
                unsigned int w3 = *(const unsigned int*)(xb + (size_t)e3.w + 2 * lane);
                edge_acc(e0, w0, a0, a1);
                edge_acc(e1, w1, a0, a1);
                edge_acc(e2, w2, a0, a1);
                edge_acc(e3, w3, a0, a1);
            }
            for (; s < cnt; s++) {
                uint4 ee = qs[wid][s];
                unsigned int xw = *(const unsigned int*)(xb + (size_t)ee.w + 2 * lane);
                edge_acc(ee, xw, a0, a1);
            }
        } else {
            if (lane < 36) {
                for (int s = 0; s < cnt; s++) {
                    uint4 ee = qs[wid][s];
                    unsigned int qw = (hc & 2) ? ((hc & 4) ? ee.z : ee.y) : ee.x;
                    // hc: 0,1 -> ee.x ; 2,3 -> ee.y ; 4,5 -> ee.z
                    if (hc == 2 || hc == 3) qw = ee.y;
                    else if (hc >= 4) qw = ee.z;
                    else qw = ee.x;
                    float qh = (hc & 1) ? hi2f(qw) : lo2f(qw);
                    float xv = u2f(xb[(size_t)ee.w + kk]);
                    acc6 += qh * xv;
                }
            }
        }
    }
    if constexpr (CIN == 128) {
        unsigned short* ar = (unsigned short*)aggv + (size_t)node * 768;
#pragma unroll
        for (int h = 0; h < HH; h++) {
            *(unsigned int*)(ar + h * 128 + 2 * lane) = pk2(a0[h] * scale, a1[h] * scale);
        }
    } else {
        if (lane < 36) ((float*)aggv)[(size_t)node * 36 + lane] = acc6 * scale;
    }
}

// ---------------- weight repacks ----------------
template <int CIN, int COUT>
__global__ void k_repack_w(const void* __restrict__ W, float* __restrict__ wstk,
                           const int* __restrict__ flags) {
    int f32 = flags[0];
    int idx = blockIdx.x * blockDim.x + threadIdx.x;
    if (idx >= HH * CIN * COUT) return;
    int f = idx % COUT;
    int m = idx / COUT;
    int h = m / CIN, k = m - h * CIN;
    wstk[idx] = ldf(W, k * (HH * COUT) + h * COUT + f, f32);
}

// bf16 Wt[n][h*128+kk] = W[kk][h*128+n]  (B^T for MFMA GEMM), n<128, K=768
__global__ void k_repack_wt(const void* __restrict__ W, unsigned short* __restrict__ wt,
                            const int* __restrict__ flags) {
    int f32 = flags[0];
    int idx = blockIdx.x * blockDim.x + threadIdx.x;
    if (idx >= 128 * 768) return;
    int f = idx / 768;
    int m = idx % 768;
    int h = m >> 7, kk = m & 127;
    wt[idx] = f2bu(ldf(W, kk * 768 + h * 128 + f, f32));
}

// ---------------- layer-1 GEMM (fp32, K=36), writes bf16 x ----------------
__global__ void __launch_bounds__(256) k_gemm_f32(const float* __restrict__ A,
                                                  const float* __restrict__ B,
                                                  const void* __restrict__ bias,
                                                  unsigned short* __restrict__ C,
                                                  int M, int K, int relu,
                                                  const int* __restrict__ flags) {
    int f32 = flags[0];
    __shared__ float As[16][68];
    __shared__ float Bs[16][128];
    int tid = threadIdx.x;
    int tx = tid & 15;
    int ty = tid >> 4;
    int bm = blockIdx.x * 64;
    int arow = tid >> 2, ak = (tid & 3) * 4;
    int brow = tid >> 4, bcol = (tid & 15) * 8;
    float acc[4][8] = {};
    for (int k0 = 0; k0 < K; k0 += 16) {
        float4 av = {0, 0, 0, 0};
        int gr = bm + arow;
        if (gr < M && (k0 + ak) < K) av = *(const float4*)(A + (size_t)gr * K + k0 + ak);
        As[ak + 0][arow] = av.x;
        As[ak + 1][arow] = av.y;
        As[ak + 2][arow] = av.z;
        As[ak + 3][arow] = av.w;
        float4 bv0 = {0, 0, 0, 0}, bv1 = {0, 0, 0, 0};
        if ((k0 + brow) < K) {
            const float* bp = B + (size_t)(k0 + brow) * 128 + bcol;
            bv0 = *(const float4*)bp;
            bv1 = *(const float4*)(bp + 4);
        }
        *(float4*)&Bs[brow][bcol]     = bv0;
        *(float4*)&Bs[brow][bcol + 4] = bv1;
        __syncthreads();
#pragma unroll
        for (int kk = 0; kk < 16; kk++) {
            float a_[4], b_[8];
#pragma unroll
            for (int j = 0; j < 4; j++) a_[j] = As[kk][ty * 4 + j];
#pragma unroll
            for (int j = 0; j < 8; j++) b_[j] = Bs[kk][tx * 8 + j];
#pragma unroll
            for (int i = 0; i < 4; i++)
#pragma unroll
                for (int j = 0; j < 8; j++) acc[i][j] = fmaf(a_[i], b_[j], acc[i][j]);
        }
        __syncthreads();
    }
#pragma unroll
    for (int i = 0; i < 4; i++) {
        int row = bm + ty * 4 + i;
        if (row >= M) continue;
#pragma unroll
        for (int j = 0; j < 8; j++) {
            int col = tx * 8 + j;
            float v = acc[i][j] + ldf(bias, col, f32);
            if (relu) v = fmaxf(v, 0.f);
            C[(size_t)row * 128 + col] = f2bu(v);
        }
    }
}

// ---------------- MFMA GEMM: C[M,128] = A[M,768]bf16 @ Wt^T + bias, ReLU ----
__global__ void __launch_bounds__(256) k_gemm_mfma(const unsigned short* __restrict__ A,
                                                   const unsigned short* __restrict__ Bt,
                                                   const void* __restrict__ bias,
                                                   unsigned short* __restrict__ C,
                                                   int M, int relu,
                                                   const int* __restrict__ flags) {
    constexpr int K = 768, BK = 64;
    __shared__ unsigned short As[64][72];
    __shared__ unsigned short Bs[128][72];
    int f32 = flags[0];
    int tid = threadIdx.x;
    int lane = tid & 63, wid = tid >> 6;
    int wm = wid & 1, wn = wid >> 1;
    int bm = blockIdx.x * 64;
    int l15 = lane & 15, lq = lane >> 4;
    f32x4 acc[2][4] = {};

    for (int k0 = 0; k0 < K; k0 += BK) {
#pragma unroll
        for (int cc = 0; cc < 2; cc++) {
            int c = tid + cc * 256;
            int r = c >> 3, kc = (c & 7) * 8;
            bf16x8 av = {};
            int gr = bm + r;
            if (gr < M) av = *(const bf16x8*)(A + (size_t)gr * K + k0 + kc);
            *(bf16x8*)&As[r][kc] = av;
        }
#pragma unroll
        for (int cc = 0; cc < 4; cc++) {
            int c = tid + cc * 256;
            int n = c >> 3, kc = (c & 7) * 8;
            *(bf16x8*)&Bs[n][kc] = *(const bf16x8*)(Bt + (size_t)n * K + k0 + kc);
        }
        __syncthreads();
#pragma unroll
        for (int ks = 0; ks < BK; ks += 32) {
            int koff = ks + lq * 8;
            bf16x8 af[2], bfr[4];
#pragma unroll
            for (int tm = 0; tm < 2; tm++)
                af[tm] = *(const bf16x8*)&As[wm * 32 + tm * 16 + l15][koff];
#pragma unroll
            for (int tn = 0; tn < 4; tn++)
                bfr[tn] = *(const bf16x8*)&Bs[wn * 64 + tn * 16 + l15][koff];
#pragma unroll
            for (int tm = 0; tm < 2; tm++)
#pragma unroll
                for (int tn = 0; tn < 4; tn++)
                    acc[tm][tn] = __builtin_amdgcn_mfma_f32_16x16x32_bf16(
                        af[tm], bfr[tn], acc[tm][tn], 0, 0, 0);
        }
        __syncthreads();
    }
#pragma unroll
    for (int tm = 0; tm < 2; tm++) {
#pragma unroll
        for (int tn = 0; tn < 4; tn++) {
            int col = wn * 64 + tn * 16 + l15;
            float bv = ldf(bias, col, f32);
#pragma unroll
            for (int r = 0; r < 4; r++) {
                int row = bm + wm * 32 + tm * 16 + lq * 4 + r;
                if (row < M) {
                    float v = acc[tm][tn][r] + bv;
                    if (relu) v = fmaxf(v, 0.f);
                    C[(size_t)row * 128 + col] = f2bu(v);
                }
            }
        }
    }
}

// ---------------- final layer ----------------
__global__ void __launch_bounds__(256) k_final(const unsigned short* __restrict__ agg,
                                               const float* __restrict__ wstk,
                                               const void* __restrict__ bias,
                                               void* __restrict__ out,
                                               const int* __restrict__ flags) {
    int f32 = flags[0];
    int node = (blockIdx.x * blockDim.x + threadIdx.x) >> 6;
    int lane = threadIdx.x & 63;
    if (node >= NN) return;
    float f0 = 0, f1 = 0, f2 = 0;
    const unsigned short* ar = agg + (size_t)node * 768;
#pragma unroll
    for (int it = 0; it < 6; it++) {
        int m = it * 128 + 2 * lane;
        unsigned int w = *(const unsigned int*)(ar + m);
        float a0 = lo2f(w);
        float a1 = hi2f(w);
        f0 += a0 * wstk[m * 3 + 0] + a1 * wstk[m * 3 + 3];
        f1 += a0 * wstk[m * 3 + 1] + a1 * wstk[m * 3 + 4];
        f2 += a0 * wstk[m * 3 + 2] + a1 * wstk[m * 3 + 5];
    }
#pragma unroll
    for (int off = 32; off > 0; off >>= 1) {
        f0 += __shfl_down(f0, off, 64);
        f1 += __shfl_down(f1, off, 64);
        f2 += __shfl_down(f2, off, 64);
    }
    if (lane == 0) {
        float r0 = f0 + ldf(bias, 0, f32);
        float r1 = f1 + ldf(bias, 1, f32);
        float r2 = f2 + ldf(bias, 2, f32);
        if (f32) {
            float* o = (float*)out;
            o[(size_t)node * 3 + 0] = r0;
            o[(size_t)node * 3 + 1] = r1;
            o[(size_t)node * 3 + 2] = r2;
        } else {
            __hip_bfloat16* o = (__hip_bfloat16*)out;
            o[(size_t)node * 3 + 0] = __float2bfloat16(r0);
            o[(size_t)node * 3 + 1] = __float2bfloat16(r1);
            o[(size_t)node * 3 + 2] = __float2bfloat16(r2);
        }
    }
}

extern "C" void kernel_launch(void* const* d_in, const int* in_sizes, int n_in,
                              void* d_out, int out_size, void* d_ws, size_t ws_size,
                              hipStream_t stream) {
    (void)in_sizes; (void)n_in; (void)out_size; (void)ws_size;
    const void* pos = d_in[0];
    const void* nrm = d_in[1];
    const int* ei = (const int*)d_in[2];
    const void* W[4] = {d_in[3], d_in[7], d_in[11], d_in[15]};
    const void* U[4] = {d_in[4], d_in[8], d_in[12], d_in[16]};
    const void* Cc[4] = {d_in[5], d_in[9], d_in[13], d_in[17]};
    const void* Bb[4] = {d_in[6], d_in[10], d_in[14], d_in[18]};

    char* wp = (char*)d_ws;
    auto alloc = [&](size_t b) { void* r = (void*)wp; wp += (b + 255) & ~(size_t)255; return r; };
    unsigned short* xA  = (unsigned short*)alloc((size_t)NN * 128 * 2);
    unsigned short* xB  = (unsigned short*)alloc((size_t)NN * 128 * 2);
    unsigned short* x0b = (unsigned short*)alloc((size_t)NN * 8 * 2);
    float* p8     = (float*)alloc((size_t)NN * 8 * 4);
    int*   counts = (int*)alloc((size_t)NN * 4);
    int*   offs   = (int*)alloc((size_t)(NN + 1) * 4);
    int*   cursor = (int*)alloc((size_t)NN * 4);
    int*   flags  = (int*)alloc(256);
    int*   ssrc   = (int*)alloc((size_t)NE * 4);
    void*  aggv   = alloc((size_t)NN * 768 * 2);
    float* wstk_f = (float*)alloc((size_t)768 * 128 * 4);
    unsigned short* wt = (unsigned short*)alloc((size_t)128 * 768 * 2);
    unsigned short* agg_h = (unsigned short*)aggv;
    float* agg_f = (float*)aggv;

    const int EB = (NE + 255) / 256;
    const int NB = (NN + 255) / 256;
    const int NWB = (NN * 64 + 255) / 256;
    const int GB = (NN + 63) / 64;

    k_detect<<<1, 256, 0, stream>>>(pos, ei, flags);
    hipMemsetAsync(counts, 0, (size_t)NN * 4, stream);
    hipMemsetAsync(cursor, 0, (size_t)NN * 4, stream);
    k_count<<<EB, 256, 0, stream>>>(ei, counts, flags);
    k_scan<<<1, 1024, 0, stream>>>(counts, offs);
    k_scatter<<<EB, 256, 0, stream>>>(ei, offs, cursor, ssrc, flags);
    k_build_x0<<<NB, 256, 0, stream>>>(pos, nrm, x0b, flags);

    // ---- layer 1: 6 -> 128, relu ----
    k_compute_p6<<<NWB, 256, 0, stream>>>(x0b, U[0], p8, flags);
    k_agg_fused<6><<<NWB, 256, 0, stream>>>(x0b, p8, Cc[0], ssrc, offs, (void*)agg_f, flags);
    k_repack_w<6, 128><<<(HH * 6 * 128 + 255) / 256, 256, 0, stream>>>(W[0], wstk_f, flags);
    k_gemm_f32<<<GB, 256, 0, stream>>>(agg_f, wstk_f, Bb[0], xA, NN, 36, 1, flags);

    // ---- layer 2: 128 -> 128, relu ----
    k_compute_p128<<<NWB, 256, 0, stream>>>(xA, U[1], p8, flags);
    k_agg_fused<128><<<NWB, 256, 0, stream>>>(xA, p8, Cc[1], ssrc, offs, (void*)agg_h, flags);
    k_repack_wt<<<(128 * 768 + 255) / 256, 256, 0, stream>>>(W[1], wt, flags);
    k_gemm_mfma<<<GB, 256, 0, stream>>>(agg_h, wt, Bb[1], xB, NN, 1, flags);

    // ---- layer 3: 128 -> 128, relu ----
    k_compute_p128<<<NWB, 256, 0, stream>>>(xB, U[2], p8, flags);
    k_agg_fused<128><<<NWB, 256, 0, stream>>>(xB, p8, Cc[2], ssrc, offs, (void*)agg_h, flags);
    k_repack_wt<<<(128 * 768 + 255) / 256, 256, 0, stream>>>(W[2], wt, flags);
    k_gemm_mfma<<<GB, 256, 0, stream>>>(agg_h, wt, Bb[2], xA, NN, 1, flags);

    // ---- layer 4: 128 -> 3 ----
    k_compute_p128<<<NWB, 256, 0, stream>>>(xA, U[3], p8, flags);
    k_agg_fused<128><<<NWB, 256, 0, stream>>>(xA, p8, Cc[3], ssrc, offs, (void*)agg_h, flags);
    k_repack_w<128, 3><<<(HH * 128 * 3 + 255) / 256, 256, 0, stream>>>(W[3], wstk_f, flags);
    k_final<<<NWB, 256, 0, stream>>>(agg_h, wstk_f, Bb[3], d_out, flags);
}